// Round 15
// baseline (34.269 us; speedup 1.0000x reference)
//
#include <hip/hip_runtime.h>
#include <math.h>

// QuantumGenerator fused single-dispatch kernel.
// out_j(x) = sum_{a,b} D_j[a*9+b] * g12[a](x0,x1) * g34[b](x2,x3),
//   g = outer products of f = (1, cos, -sin) per wire.
// Phase A (per block, redundant, ~0.5us): shfl-parallel build of the 4x81
//   coefficient table into LDS (j-major rows padded to 84).
// Phase B (R12 structure): wave w owns j=w; hoists its 81 coefficients into
//   named float4 VGPRs (21 uniform ds_read_b128 broadcasts); element loop has
//   zero table traffic; 4 j-columns recombined via padded LDS transpose.
// Removes the 2nd launch + precompute dispatch + inter-kernel drain entirely.

__global__ __launch_bounds__(256, 3) void qg_fused(
    const float4* __restrict__ noise,   // [B] float4 (x0..x3)
    const float*  __restrict__ qw,      // [2][4][3]
    const float*  __restrict__ Wm,      // [4][4]
    const float*  __restrict__ bv,      // [4]
    float4* __restrict__ out,           // [B] float4
    int B)
{
  __shared__ float  gm[24][8];
  __shared__ float2 Ul[16][16];
  __shared__ float  wj[4][16];
  __shared__ float2 A[4][16][16];
  __shared__ float  tbl[4*84];          // j-major rows, padded to 84
  __shared__ float  tr[256][5];         // elem-major recombination (padded)
  const int tid = threadIdx.x;

  // ======== Phase A: build table in LDS ========
  if (tid < 24) {
    const float phi = qw[tid*3 + 0];
    const float th  = qw[tid*3 + 1];
    const float om  = qw[tid*3 + 2];
    const float st = __sinf(0.5f*th),       ct = __cosf(0.5f*th);
    const float sa = __sinf(0.5f*(phi+om)), ca = __cosf(0.5f*(phi+om));
    const float sd = __sinf(0.5f*(phi-om)), cd = __cosf(0.5f*(phi-om));
    gm[tid][0] =  ca*ct; gm[tid][1] = -sa*ct;   // m00
    gm[tid][2] = -cd*st; gm[tid][3] = -sd*st;   // m01
    gm[tid][4] =  cd*st; gm[tid][5] = -sd*st;   // m10
    gm[tid][6] =  ca*ct; gm[tid][7] =  sa*ct;   // m11
  }
  if (tid >= 192) {
    const int j = (tid - 192) >> 4, k = tid & 15;
    float s = 0.f;
    #pragma unroll
    for (int i = 0; i < 4; ++i)
      s += Wm[j*4 + i] * (((k >> (3 - i)) & 1) ? -1.f : 1.f);
    wj[j][k] = s;
  }
  __syncthreads();

  {  // U build: one matrix element per thread, shfl butterflies (16-lane groups)
    const int col = tid >> 4, row = tid & 15;
    float vr = (row == col) ? 1.f : 0.f, vi = 0.f;
    #pragma unroll
    for (int l = 0; l < 2; ++l) {
      #pragma unroll
      for (int w = 0; w < 4; ++w) {
        const int g = l*4 + w;
        const float m00r = gm[g][0], m00i = gm[g][1];
        const float m01r = gm[g][2], m01i = gm[g][3];
        const float m10r = gm[g][4], m10i = gm[g][5];
        const float m11r = gm[g][6], m11i = gm[g][7];
        const int mask = 8 >> w;
        const float pr = __shfl_xor(vr, mask);
        const float pi = __shfl_xor(vi, mask);
        float nr, ni;
        if (!(row & mask)) {
          nr = m00r*vr - m00i*vi + m01r*pr - m01i*pi;
          ni = m00r*vi + m00i*vr + m01r*pi + m01i*pr;
        } else {
          nr = m10r*pr - m10i*pi + m11r*vr - m11i*vi;
          ni = m10r*pi + m10i*pr + m11r*vi + m11i*vr;
        }
        vr = nr; vi = ni;
      }
      const int r = l + 1;  // StronglyEntanglingLayers ranges for 2 layers
      #pragma unroll
      for (int w = 0; w < 4; ++w) {
        const int t  = (w + r) & 3;
        const int cm = 8 >> w, tm = 8 >> t;
        const float pr = __shfl_xor(vr, tm);
        const float pi = __shfl_xor(vi, tm);
        if (row & cm) { vr = pr; vi = pi; }
      }
    }
    Ul[row][col] = make_float2(vr, vi);
  }
  __syncthreads();

  {  // A[j][s][t] = sum_k conj(U[k][s]) wj[j][k] U[k][t]
    const int s = tid >> 4, t = tid & 15;
    float ar[4] = {0,0,0,0}, ai[4] = {0,0,0,0};
    #pragma unroll
    for (int k = 0; k < 16; ++k) {
      const float2 us = Ul[k][s], ut = Ul[k][t];
      const float pr = us.x*ut.x + us.y*ut.y;
      const float pi = us.x*ut.y - us.y*ut.x;
      #pragma unroll
      for (int j = 0; j < 4; ++j) { ar[j] += wj[j][k]*pr; ai[j] += wj[j][k]*pi; }
    }
    #pragma unroll
    for (int j = 0; j < 4; ++j) A[j][s][t] = make_float2(ar[j], ai[j]);
  }
  __syncthreads();

  // D_j[p] = (1/16) Tr(A_j sigma_p); store j-major tbl[j*84 + p]
  for (int item = tid; item < 324; item += 256) {
    const int j = item / 81, p = item % 81;
    const int p1 = p / 27, p2 = (p / 9) % 3, p3 = (p / 3) % 3, p4 = p % 3;
    int ym = 0, ny = 0;
    if (p1 == 2) { ym |= 8; ++ny; }
    if (p2 == 2) { ym |= 4; ++ny; }
    if (p3 == 2) { ym |= 2; ++ny; }
    if (p4 == 2) { ym |= 1; ++ny; }
    float sum = 0.f;
    for (int t = 0; t < 16; ++t) {
      const int t0 = (t>>3)&1, t1 = (t>>2)&1, t2 = (t>>1)&1, t3 = t&1;
      float sgn = 1.f;
      if      (p1 == 1) sgn *= t0 ? -1.f : 1.f;
      else if (p1 == 2) sgn *= t0 ?  1.f : -1.f;
      if      (p2 == 1) sgn *= t1 ? -1.f : 1.f;
      else if (p2 == 2) sgn *= t1 ?  1.f : -1.f;
      if      (p3 == 1) sgn *= t2 ? -1.f : 1.f;
      else if (p3 == 2) sgn *= t2 ?  1.f : -1.f;
      if      (p4 == 1) sgn *= t3 ? -1.f : 1.f;
      else if (p4 == 2) sgn *= t3 ?  1.f : -1.f;
      const float2 ae = A[j][t ^ ym][t];
      const int m = ny & 3;
      const float re = (m == 0) ? ae.x : (m == 1) ? -ae.y : (m == 2) ? -ae.x : ae.y;
      sum += sgn * re;
    }
    sum *= 0.0625f;
    if (p == 0) sum += bv[j];
    tbl[j*84 + p] = sum;
  }
  __syncthreads();

  // ======== Phase B: j-per-wave, table in named float4 VGPRs ========
  const int wv   = tid >> 6;            // wave id == output column j
  const int lane = tid & 63;

#define Q0  v0.x
#define Q1  v0.y
#define Q2  v0.z
#define Q3  v0.w
#define Q4  v1.x
#define Q5  v1.y
#define Q6  v1.z
#define Q7  v1.w
#define Q8  v2.x
#define Q9  v2.y
#define Q10 v2.z
#define Q11 v2.w
#define Q12 v3.x
#define Q13 v3.y
#define Q14 v3.z
#define Q15 v3.w
#define Q16 v4.x
#define Q17 v4.y
#define Q18 v4.z
#define Q19 v4.w
#define Q20 v5.x
#define Q21 v5.y
#define Q22 v5.z
#define Q23 v5.w
#define Q24 v6.x
#define Q25 v6.y
#define Q26 v6.z
#define Q27 v6.w
#define Q28 v7.x
#define Q29 v7.y
#define Q30 v7.z
#define Q31 v7.w
#define Q32 v8.x
#define Q33 v8.y
#define Q34 v8.z
#define Q35 v8.w
#define Q36 v9.x
#define Q37 v9.y
#define Q38 v9.z
#define Q39 v9.w
#define Q40 v10.x
#define Q41 v10.y
#define Q42 v10.z
#define Q43 v10.w
#define Q44 v11.x
#define Q45 v11.y
#define Q46 v11.z
#define Q47 v11.w
#define Q48 v12.x
#define Q49 v12.y
#define Q50 v12.z
#define Q51 v12.w
#define Q52 v13.x
#define Q53 v13.y
#define Q54 v13.z
#define Q55 v13.w
#define Q56 v14.x
#define Q57 v14.y
#define Q58 v14.z
#define Q59 v14.w
#define Q60 v15.x
#define Q61 v15.y
#define Q62 v15.z
#define Q63 v15.w
#define Q64 v16.x
#define Q65 v16.y
#define Q66 v16.z
#define Q67 v16.w
#define Q68 v17.x
#define Q69 v17.y
#define Q70 v17.z
#define Q71 v17.w
#define Q72 v18.x
#define Q73 v18.y
#define Q74 v18.z
#define Q75 v18.w
#define Q76 v19.x
#define Q77 v19.y
#define Q78 v19.z
#define Q79 v19.w
#define Q80 q80

  // Wave-broadcast the j-row into named float4 registers (uniform ds_read_b128).
  const float4* Tj = (const float4*)&tbl[wv * 84];
  const float4 v0  = Tj[0],  v1  = Tj[1],  v2  = Tj[2],  v3  = Tj[3];
  const float4 v4  = Tj[4],  v5  = Tj[5],  v6  = Tj[6],  v7  = Tj[7];
  const float4 v8  = Tj[8],  v9  = Tj[9],  v10 = Tj[10], v11 = Tj[11];
  const float4 v12 = Tj[12], v13 = Tj[13], v14 = Tj[14], v15 = Tj[15];
  const float4 v16 = Tj[16], v17 = Tj[17], v18 = Tj[18], v19 = Tj[19];
  const float q80  = tbl[wv * 84 + 80];

  const int Bm1 = B - 1;

  // 2048 blocks x 512 elems: 2 iters of 256 elems per block.
  int base = blockIdx.x * 512;
  #pragma unroll
  for (int it = 0; it < 2; ++it, base += 256) {
    #pragma unroll
    for (int s = 0; s < 4; ++s) {
      const int e = base + s*64 + lane;
      const float4 x = noise[min(e, Bm1)];
      const float s0 = __sinf(x.x), c0 = __cosf(x.x);
      const float s1 = __sinf(x.y), c1 = __cosf(x.y);
      const float s2 = __sinf(x.z), c2 = __cosf(x.z);
      const float s3 = __sinf(x.w), c3 = __cosf(x.w);

      // f = (1, cos, -sin); g12[a]=f1[a/3]*f2[a%3]; g34[b]=f3[b/3]*f4[b%3]
      const float g34_1 =  c3,     g34_2 = -s3,
                  g34_3 =  c2,     g34_4 =  c2*c3,  g34_5 = -c2*s3,
                  g34_6 = -s2,     g34_7 = -s2*c3,  g34_8 =  s2*s3;
      const float g12_1 =  c1,     g12_2 = -s1,
                  g12_3 =  c0,     g12_4 =  c0*c1,  g12_5 = -c0*s1,
                  g12_6 = -s0,     g12_7 = -s0*c1,  g12_8 =  s0*s1;

      float acc, h;
#define ABLK(A0,A1,A2,A3,A4,A5,A6,A7,A8) {      \
      h = A0;                                   \
      h = fmaf(A1, g34_1, h);                   \
      h = fmaf(A2, g34_2, h);                   \
      h = fmaf(A3, g34_3, h);                   \
      h = fmaf(A4, g34_4, h);                   \
      h = fmaf(A5, g34_5, h);                   \
      h = fmaf(A6, g34_6, h);                   \
      h = fmaf(A7, g34_7, h);                   \
      h = fmaf(A8, g34_8, h); }

      ABLK(Q0, Q1, Q2, Q3, Q4, Q5, Q6, Q7, Q8)          acc = h;
      ABLK(Q9, Q10,Q11,Q12,Q13,Q14,Q15,Q16,Q17)         acc = fmaf(g12_1, h, acc);
      ABLK(Q18,Q19,Q20,Q21,Q22,Q23,Q24,Q25,Q26)         acc = fmaf(g12_2, h, acc);
      ABLK(Q27,Q28,Q29,Q30,Q31,Q32,Q33,Q34,Q35)         acc = fmaf(g12_3, h, acc);
      ABLK(Q36,Q37,Q38,Q39,Q40,Q41,Q42,Q43,Q44)         acc = fmaf(g12_4, h, acc);
      ABLK(Q45,Q46,Q47,Q48,Q49,Q50,Q51,Q52,Q53)         acc = fmaf(g12_5, h, acc);
      ABLK(Q54,Q55,Q56,Q57,Q58,Q59,Q60,Q61,Q62)         acc = fmaf(g12_6, h, acc);
      ABLK(Q63,Q64,Q65,Q66,Q67,Q68,Q69,Q70,Q71)         acc = fmaf(g12_7, h, acc);
      ABLK(Q72,Q73,Q74,Q75,Q76,Q77,Q78,Q79,Q80)         acc = fmaf(g12_8, h, acc);
#undef ABLK

      if (wv == 0) acc = fabsf(acc) + 0.001f;   // wave-uniform branch
      tr[s*64 + lane][wv] = acc;
    }
    __syncthreads();
    {
      const int e = base + tid;
      const float o0 = tr[tid][0], o1 = tr[tid][1];
      const float o2 = tr[tid][2], o3 = tr[tid][3];
      if (e < B) out[e] = make_float4(o0, o1, o2, o3);
    }
    __syncthreads();
  }
}

extern "C" void kernel_launch(void* const* d_in, const int* in_sizes, int n_in,
                              void* d_out, int out_size, void* d_ws, size_t ws_size,
                              hipStream_t stream) {
  const float* noise = (const float*)d_in[0];   // [B,4]
  const float* qw    = (const float*)d_in[1];   // [2,4,3]
  const float* Wm    = (const float*)d_in[2];   // [4,4]
  const float* bv    = (const float*)d_in[3];   // [4]
  const int B = in_sizes[0] / 4;

  const int blocks = (B + 511) / 512;           // 2048 for B = 1048576
  hipLaunchKernelGGL(qg_fused, dim3(blocks), dim3(256), 0, stream,
                     (const float4*)noise, qw, Wm, bv, (float4*)d_out, B);
}

// Round 16
// 22.249 us; speedup vs baseline: 1.5402x; 1.5402x over previous
//
#include <hip/hip_runtime.h>
#include <math.h>

// QuantumGenerator: 4-qubit, 2-layer StronglyEntanglingLayers circuit + Linear(4,4).
// out_j(x) = sum_{p in {I,Z,Y}^4} D_j[p] * prod_w f_{p_w}(x_w),  f = (1, cos, -sin).
// qg_precompute (1 block, shfl-parallel): builds 81x4 coefficient table D in d_ws.
// qg_main (R16): E=2 elements/thread as ext_vector_type(2) floats; the 324-FMA
//   contraction becomes <2 x float> fma -> v_pk_fma_f32 (2x fp32/instr), halving
//   VALU issue. Table via constant-AS s_loads (R7 path). Trig scalar.

typedef float v2f __attribute__((ext_vector_type(2)));

__device__ __forceinline__ v2f splat2(float s) { v2f r; r.x = s; r.y = s; return r; }

__global__ __launch_bounds__(256) void qg_precompute(
    const float* __restrict__ qw,   // [2][4][3] (phi, theta, omega)
    const float* __restrict__ Wm,   // [4][4]
    const float* __restrict__ bv,   // [4]
    float* __restrict__ Dcoef)      // [81][4]
{
  __shared__ float  gm[24][8];      // per-gate 2x2 complex matrix
  __shared__ float2 Ul[16][16];     // U[k][col]
  __shared__ float  wj[4][16];
  __shared__ float2 A[4][16][16];
  const int tid = threadIdx.x;

  if (tid < 24) {
    const float phi = qw[tid*3 + 0];
    const float th  = qw[tid*3 + 1];
    const float om  = qw[tid*3 + 2];
    const float st = __sinf(0.5f*th),       ct = __cosf(0.5f*th);
    const float sa = __sinf(0.5f*(phi+om)), ca = __cosf(0.5f*(phi+om));
    const float sd = __sinf(0.5f*(phi-om)), cd = __cosf(0.5f*(phi-om));
    gm[tid][0] =  ca*ct; gm[tid][1] = -sa*ct;   // m00
    gm[tid][2] = -cd*st; gm[tid][3] = -sd*st;   // m01
    gm[tid][4] =  cd*st; gm[tid][5] = -sd*st;   // m10
    gm[tid][6] =  ca*ct; gm[tid][7] =  sa*ct;   // m11
  }
  if (tid >= 192) {
    const int j = (tid - 192) >> 4, k = tid & 15;
    float s = 0.f;
    #pragma unroll
    for (int i = 0; i < 4; ++i)
      s += Wm[j*4 + i] * (((k >> (3 - i)) & 1) ? -1.f : 1.f);
    wj[j][k] = s;
  }
  __syncthreads();

  {  // U build: one matrix element per thread, shfl butterflies (16-lane groups)
    const int col = tid >> 4, row = tid & 15;
    float vr = (row == col) ? 1.f : 0.f, vi = 0.f;
    #pragma unroll
    for (int l = 0; l < 2; ++l) {
      #pragma unroll
      for (int w = 0; w < 4; ++w) {
        const int g = l*4 + w;
        const float m00r = gm[g][0], m00i = gm[g][1];
        const float m01r = gm[g][2], m01i = gm[g][3];
        const float m10r = gm[g][4], m10i = gm[g][5];
        const float m11r = gm[g][6], m11i = gm[g][7];
        const int mask = 8 >> w;
        const float pr = __shfl_xor(vr, mask);
        const float pi = __shfl_xor(vi, mask);
        float nr, ni;
        if (!(row & mask)) {
          nr = m00r*vr - m00i*vi + m01r*pr - m01i*pi;
          ni = m00r*vi + m00i*vr + m01r*pi + m01i*pr;
        } else {
          nr = m10r*pr - m10i*pi + m11r*vr - m11i*vi;
          ni = m10r*pi + m10i*pr + m11r*vi + m11i*vr;
        }
        vr = nr; vi = ni;
      }
      const int r = l + 1;  // StronglyEntanglingLayers ranges for 2 layers
      #pragma unroll
      for (int w = 0; w < 4; ++w) {
        const int t  = (w + r) & 3;
        const int cm = 8 >> w, tm = 8 >> t;
        const float pr = __shfl_xor(vr, tm);
        const float pi = __shfl_xor(vi, tm);
        if (row & cm) { vr = pr; vi = pi; }
      }
    }
    Ul[row][col] = make_float2(vr, vi);
  }
  __syncthreads();

  {  // A[j][s][t] = sum_k conj(U[k][s]) wj[j][k] U[k][t]
    const int s = tid >> 4, t = tid & 15;
    float ar[4] = {0,0,0,0}, ai[4] = {0,0,0,0};
    #pragma unroll
    for (int k = 0; k < 16; ++k) {
      const float2 us = Ul[k][s], ut = Ul[k][t];
      const float pr = us.x*ut.x + us.y*ut.y;
      const float pi = us.x*ut.y - us.y*ut.x;
      #pragma unroll
      for (int j = 0; j < 4; ++j) { ar[j] += wj[j][k]*pr; ai[j] += wj[j][k]*pi; }
    }
    #pragma unroll
    for (int j = 0; j < 4; ++j) A[j][s][t] = make_float2(ar[j], ai[j]);
  }
  __syncthreads();

  // D_j[p] = (1/16) Tr(A_j sigma_p), sigma in {I,Z,Y}^4
  for (int item = tid; item < 324; item += 256) {
    const int j = item / 81, p = item % 81;
    const int p1 = p / 27, p2 = (p / 9) % 3, p3 = (p / 3) % 3, p4 = p % 3;
    int ym = 0, ny = 0;
    if (p1 == 2) { ym |= 8; ++ny; }
    if (p2 == 2) { ym |= 4; ++ny; }
    if (p3 == 2) { ym |= 2; ++ny; }
    if (p4 == 2) { ym |= 1; ++ny; }
    float sum = 0.f;
    for (int t = 0; t < 16; ++t) {
      const int t0 = (t>>3)&1, t1 = (t>>2)&1, t2 = (t>>1)&1, t3 = t&1;
      float sgn = 1.f;
      if      (p1 == 1) sgn *= t0 ? -1.f : 1.f;
      else if (p1 == 2) sgn *= t0 ?  1.f : -1.f;
      if      (p2 == 1) sgn *= t1 ? -1.f : 1.f;
      else if (p2 == 2) sgn *= t1 ?  1.f : -1.f;
      if      (p3 == 1) sgn *= t2 ? -1.f : 1.f;
      else if (p3 == 2) sgn *= t2 ?  1.f : -1.f;
      if      (p4 == 1) sgn *= t3 ? -1.f : 1.f;
      else if (p4 == 2) sgn *= t3 ?  1.f : -1.f;
      const float2 ae = A[j][t ^ ym][t];
      const int m = ny & 3;
      const float re = (m == 0) ? ae.x : (m == 1) ? -ae.y : (m == 2) ? -ae.x : ae.y;
      sum += sgn * re;
    }
    sum *= 0.0625f;
    if (p == 0) sum += bv[j];
    Dcoef[p*4 + j] = sum;
  }
}

#define QG_CONST __attribute__((address_space(4)))

__global__ __launch_bounds__(256, 4) void qg_main(
    const float4* __restrict__ noise,   // [B] float4 (x0..x3)
    const float*  __restrict__ Dg,      // [81][4] coefficient table
    float4* __restrict__ out,           // [B] float4
    int B)
{
  // Constant-AS view of D: scalar dereferences compile to s_load (SMEM pipe).
  const QG_CONST float* D = (const QG_CONST float*)(unsigned long long)Dg;

  const int tid = threadIdx.x;
  const int ia  = blockIdx.x * 512 + tid;   // elem A
  const int ib  = ia + 256;                 // elem B
  const int Bm1 = B - 1;
  const float4 xa = noise[min(ia, Bm1)];
  const float4 xb = noise[min(ib, Bm1)];

  // Scalar fast trig (v_sin_f32/v_cos_f32), then pack per-wire vectors.
  v2f s0v, c0v, s1v, c1v, s2v, c2v, s3v, c3v;
  s0v.x = __sinf(xa.x); s0v.y = __sinf(xb.x);
  c0v.x = __cosf(xa.x); c0v.y = __cosf(xb.x);
  s1v.x = __sinf(xa.y); s1v.y = __sinf(xb.y);
  c1v.x = __cosf(xa.y); c1v.y = __cosf(xb.y);
  s2v.x = __sinf(xa.z); s2v.y = __sinf(xb.z);
  c2v.x = __cosf(xa.z); c2v.y = __cosf(xb.z);
  s3v.x = __sinf(xa.w); s3v.y = __sinf(xb.w);
  c3v.x = __cosf(xa.w); c3v.y = __cosf(xb.w);

  // f = (1, cos, -sin); g12[a]=f1[a/3]*f2[a%3]; g34[b]=f3[b/3]*f4[b%3]
  const v2f g34_1 =  c3v,       g34_2 = -s3v,
            g34_3 =  c2v,       g34_4 =  c2v*c3v, g34_5 = -(c2v*s3v),
            g34_6 = -s2v,       g34_7 = -(s2v*c3v), g34_8 = s2v*s3v;
  const v2f g12_1 =  c1v,       g12_2 = -s1v,
            g12_3 =  c0v,       g12_4 =  c0v*c1v, g12_5 = -(c0v*s1v),
            g12_6 = -s0v,       g12_7 = -(s0v*c1v), g12_8 = s0v*s1v;

  v2f h0, h1, h2, h3, acc0, acc1, acc2, acc3;

#define FMA2(a,b,c) __builtin_elementwise_fma((a), (b), (c))
#define HT(a,b,g) {                                                  \
    const float qx = D[((a)*9+(b))*4+0], qy = D[((a)*9+(b))*4+1];    \
    const float qz = D[((a)*9+(b))*4+2], qw_ = D[((a)*9+(b))*4+3];   \
    h0 = FMA2(splat2(qx),  (g), h0); h1 = FMA2(splat2(qy),  (g), h1); \
    h2 = FMA2(splat2(qz),  (g), h2); h3 = FMA2(splat2(qw_), (g), h3); }
#define HB(a) {                                                      \
    h0 = splat2(D[(a)*36+0]); h1 = splat2(D[(a)*36+1]);              \
    h2 = splat2(D[(a)*36+2]); h3 = splat2(D[(a)*36+3]); }            \
    HT(a,1,g34_1) HT(a,2,g34_2) HT(a,3,g34_3) HT(a,4,g34_4)          \
    HT(a,5,g34_5) HT(a,6,g34_6) HT(a,7,g34_7) HT(a,8,g34_8)
#define ACC(g) { acc0 = FMA2((g), h0, acc0); acc1 = FMA2((g), h1, acc1); \
                 acc2 = FMA2((g), h2, acc2); acc3 = FMA2((g), h3, acc3); }

  HB(0) acc0 = h0; acc1 = h1; acc2 = h2; acc3 = h3;
  HB(1) ACC(g12_1)
  HB(2) ACC(g12_2)
  HB(3) ACC(g12_3)
  HB(4) ACC(g12_4)
  HB(5) ACC(g12_5)
  HB(6) ACC(g12_6)
  HB(7) ACC(g12_7)
  HB(8) ACC(g12_8)

#undef HT
#undef HB
#undef ACC
#undef FMA2

  if (ia < B)
    out[ia] = make_float4(fabsf(acc0.x) + 0.001f, acc1.x, acc2.x, acc3.x);
  if (ib < B)
    out[ib] = make_float4(fabsf(acc0.y) + 0.001f, acc1.y, acc2.y, acc3.y);
}

extern "C" void kernel_launch(void* const* d_in, const int* in_sizes, int n_in,
                              void* d_out, int out_size, void* d_ws, size_t ws_size,
                              hipStream_t stream) {
  const float* noise = (const float*)d_in[0];   // [B,4]
  const float* qw    = (const float*)d_in[1];   // [2,4,3]
  const float* Wm    = (const float*)d_in[2];   // [4,4]
  const float* bv    = (const float*)d_in[3];   // [4]
  float* Dcoef = (float*)d_ws;                  // 81*4 floats
  const int B = in_sizes[0] / 4;

  hipLaunchKernelGGL(qg_precompute, dim3(1), dim3(256), 0, stream, qw, Wm, bv, Dcoef);

  const int blocks = (B + 511) / 512;           // 2048 for B = 1048576
  hipLaunchKernelGGL(qg_main, dim3(blocks), dim3(256), 0, stream,
                     (const float4*)noise, (const float*)Dcoef, (float4*)d_out, B);
}